// Round 5
// baseline (243.490 us; speedup 1.0000x reference)
//
#include <hip/hip_runtime.h>
#include <hip/hip_bf16.h>

typedef unsigned int u32;
typedef unsigned short u16;
typedef __attribute__((ext_vector_type(8))) __bf16 bf16x8;
typedef __attribute__((ext_vector_type(4))) float f32x4;

#define N_CAP 10
#define D_CAP 16
#define NN 160          // N_CAP * D_CAP
#define KK 2048
#define BM 64           // rows per block
#define BK 32           // K per step (= one MFMA K)
#define NSTEPS (KK / BK)        // 64
#define THREADS 640             // 10 waves
#define LDST 40                 // u16 stride per As row (32 data + 8 pad); rows 80 B, 16B-aligned
#define AS_TILE (BM * LDST)     // 2560 u16 per tile (hi or lo)
#define HAT_STRIDE 164          // f32 words per hat row (160 + 4 pad)
#define SMEM_BYTES (BM * HAT_STRIDE * 4)   // 41984 B; staging region = 10240 B

__device__ __forceinline__ u32 pack_hi(float f0, float f1) {
  // pack bf16-truncations of f0 (low16) and f1 (high16)
  u32 u0 = __builtin_bit_cast(u32, f0), u1 = __builtin_bit_cast(u32, f1);
  return (u0 >> 16) | (u1 & 0xFFFF0000u);
}
__device__ __forceinline__ float hi_part(float f) {
  u32 u = __builtin_bit_cast(u32, f) & 0xFFFF0000u;
  return __builtin_bit_cast(float, u);
}
union U4B8 { uint4 u; bf16x8 b; };

__global__ __launch_bounds__(THREADS, 3) void capsule_fused(
    const float* __restrict__ X, const float* __restrict__ W, float* __restrict__ out) {
  __shared__ __align__(16) char smem[SMEM_BYTES];
  u16* As_hi = (u16*)smem;                // [64][40] u16 : As_hi[m][k]
  u16* As_lo = As_hi + AS_TILE;           // [64][40] u16
  float* hat = (float*)smem;              // reused after GEMM: [64][164] f32

  const int t = threadIdx.x;
  const int rbase = blockIdx.x * BM;
  const int lane = t & 63;
  const int w = t >> 6;                 // wave 0..9
  const int wip = (w >= 5) ? 1 : 0;     // row half: rows 32*wip..+32
  const int wjp = w - 5 * wip;          // col group: cols 32*wjp..+32
  const int l15 = lane & 15;
  const int q = lane >> 4;              // 0..3

  // ---- A loader (t < 256): X[rbase + (t>>2)][s*32 + (t&3)*8 .. +8) ----
  const int ar = t >> 2;
  const int ak = (t & 3) * 8;
  const float* gA = X + (size_t)(rbase + ar) * KK + ak;

  // ---- B: per-lane direct global loads (W is L2/L3-resident, 1.3 MB) ----
  // fragment element j of half i: W[(s*32 + q*8 + j)][32*wjp + 16*i + l15]
  const float* gB = W + (q * 8) * NN + 32 * wjp + l15;   // j-step: +NN, i-step: +16

  f32x4 acc00 = {0.f,0.f,0.f,0.f}, acc01 = {0.f,0.f,0.f,0.f};
  f32x4 acc10 = {0.f,0.f,0.f,0.f}, acc11 = {0.f,0.f,0.f,0.f};

  // ---- prologue: A prefetch for steps 0,1; B prefetch for step 0 ----
  float4 pa0A, pa1A, pa0B, pa1B;
  if (t < 256) {
    pa0A = *(const float4*)(gA);            pa1A = *(const float4*)(gA + 4);
    pa0B = *(const float4*)(gA + BK);       pa1B = *(const float4*)(gA + BK + 4);
  }
  float buA[16], buB[16];
#pragma unroll
  for (int j = 0; j < 8; ++j) { buA[j] = gB[j * NN]; buA[8 + j] = gB[16 + j * NN]; }

#define STEP(S, PA0, PA1, BU, BNXT)                                              \
  {                                                                              \
    __syncthreads();                          /* prior A-frag reads complete */  \
    if (t < 256) {                                                               \
      uint4 hi, lo;                                                              \
      hi.x = pack_hi(PA0.x, PA0.y); hi.y = pack_hi(PA0.z, PA0.w);                \
      hi.z = pack_hi(PA1.x, PA1.y); hi.w = pack_hi(PA1.z, PA1.w);                \
      float l0 = PA0.x - hi_part(PA0.x), l1 = PA0.y - hi_part(PA0.y);            \
      float l2 = PA0.z - hi_part(PA0.z), l3 = PA0.w - hi_part(PA0.w);            \
      float l4 = PA1.x - hi_part(PA1.x), l5 = PA1.y - hi_part(PA1.y);            \
      float l6 = PA1.z - hi_part(PA1.z), l7 = PA1.w - hi_part(PA1.w);            \
      lo.x = pack_hi(l0, l1); lo.y = pack_hi(l2, l3);                            \
      lo.z = pack_hi(l4, l5); lo.w = pack_hi(l6, l7);                            \
      *(uint4*)(As_hi + ar * LDST + ak) = hi;                                    \
      *(uint4*)(As_lo + ar * LDST + ak) = lo;                                    \
    }                                                                            \
    __syncthreads();                          /* As visible */                   \
    if (t < 256 && (S) + 2 < NSTEPS) {                                           \
      PA0 = *(const float4*)(gA + ((S) + 2) * BK);                               \
      PA1 = *(const float4*)(gA + ((S) + 2) * BK + 4);                           \
    }                                                                            \
    if ((S) + 1 < NSTEPS) {                                                      \
      const float* b = gB + ((S) + 1) * (BK * NN);                               \
      _Pragma("unroll")                                                          \
      for (int j = 0; j < 8; ++j) { BNXT[j] = b[j * NN]; BNXT[8 + j] = b[16 + j * NN]; } \
    }                                                                            \
    U4B8 bh0, bl0, bh1, bl1;                                                     \
    bh0.u.x = pack_hi(BU[0], BU[1]);  bh0.u.y = pack_hi(BU[2], BU[3]);           \
    bh0.u.z = pack_hi(BU[4], BU[5]);  bh0.u.w = pack_hi(BU[6], BU[7]);           \
    bh1.u.x = pack_hi(BU[8], BU[9]);  bh1.u.y = pack_hi(BU[10], BU[11]);         \
    bh1.u.z = pack_hi(BU[12], BU[13]); bh1.u.w = pack_hi(BU[14], BU[15]);        \
    float lb[16];                                                                \
    _Pragma("unroll")                                                            \
    for (int j = 0; j < 16; ++j) lb[j] = BU[j] - hi_part(BU[j]);                 \
    bl0.u.x = pack_hi(lb[0], lb[1]);  bl0.u.y = pack_hi(lb[2], lb[3]);           \
    bl0.u.z = pack_hi(lb[4], lb[5]);  bl0.u.w = pack_hi(lb[6], lb[7]);           \
    bl1.u.x = pack_hi(lb[8], lb[9]);  bl1.u.y = pack_hi(lb[10], lb[11]);         \
    bl1.u.z = pack_hi(lb[12], lb[13]); bl1.u.w = pack_hi(lb[14], lb[15]);        \
    bf16x8 ah0 = *(const bf16x8*)(As_hi + (32 * wip + l15) * LDST + q * 8);      \
    bf16x8 ah1 = *(const bf16x8*)(As_hi + (32 * wip + 16 + l15) * LDST + q * 8); \
    bf16x8 al0 = *(const bf16x8*)(As_lo + (32 * wip + l15) * LDST + q * 8);      \
    bf16x8 al1 = *(const bf16x8*)(As_lo + (32 * wip + 16 + l15) * LDST + q * 8); \
    acc00 = __builtin_amdgcn_mfma_f32_16x16x32_bf16(ah0, bh0.b, acc00, 0, 0, 0); \
    acc00 = __builtin_amdgcn_mfma_f32_16x16x32_bf16(ah0, bl0.b, acc00, 0, 0, 0); \
    acc00 = __builtin_amdgcn_mfma_f32_16x16x32_bf16(al0, bh0.b, acc00, 0, 0, 0); \
    acc01 = __builtin_amdgcn_mfma_f32_16x16x32_bf16(ah0, bh1.b, acc01, 0, 0, 0); \
    acc01 = __builtin_amdgcn_mfma_f32_16x16x32_bf16(ah0, bl1.b, acc01, 0, 0, 0); \
    acc01 = __builtin_amdgcn_mfma_f32_16x16x32_bf16(al0, bh1.b, acc01, 0, 0, 0); \
    acc10 = __builtin_amdgcn_mfma_f32_16x16x32_bf16(ah1, bh0.b, acc10, 0, 0, 0); \
    acc10 = __builtin_amdgcn_mfma_f32_16x16x32_bf16(ah1, bl0.b, acc10, 0, 0, 0); \
    acc10 = __builtin_amdgcn_mfma_f32_16x16x32_bf16(al1, bh0.b, acc10, 0, 0, 0); \
    acc11 = __builtin_amdgcn_mfma_f32_16x16x32_bf16(ah1, bh1.b, acc11, 0, 0, 0); \
    acc11 = __builtin_amdgcn_mfma_f32_16x16x32_bf16(ah1, bl1.b, acc11, 0, 0, 0); \
    acc11 = __builtin_amdgcn_mfma_f32_16x16x32_bf16(al1, bh1.b, acc11, 0, 0, 0); \
  }

  for (int s = 0; s < NSTEPS; s += 2) {
    STEP(s,     pa0A, pa1A, buA, buB)
    STEP(s + 1, pa0B, pa1B, buB, buA)
  }
#undef STEP

  __syncthreads();                      // all LDS reads done; reuse smem as hat
#pragma unroll
  for (int r = 0; r < 4; ++r) {
    // C/D layout (m89/m91): col(n) = lane&15, row(m) = (lane>>4)*4 + reg
    const int rowb = 32 * wip + 4 * q + r;
    const int colb = 32 * wjp + l15;
    hat[rowb * HAT_STRIDE + colb]             = acc00[r];
    hat[rowb * HAT_STRIDE + colb + 16]        = acc01[r];
    hat[(rowb + 16) * HAT_STRIDE + colb]      = acc10[r];
    hat[(rowb + 16) * HAT_STRIDE + colb + 16] = acc11[r];
  }
  __syncthreads();

  // ---- routing: 1 thread per row, fully in-thread (proven in R4) ----
  if (t < BM) {
    const int r = t;
    float bb[N_CAP];
#pragma unroll
    for (int n = 0; n < N_CAP; ++n) bb[n] = 0.f;
    float v[D_CAP];
#pragma unroll
    for (int it = 0; it < 3; ++it) {
      float mx = bb[0];
#pragma unroll
      for (int n = 1; n < N_CAP; ++n) mx = fmaxf(mx, bb[n]);
      float c[N_CAP], se = 0.f;
#pragma unroll
      for (int n = 0; n < N_CAP; ++n) { c[n] = __expf(bb[n] - mx); se += c[n]; }
      const float inv = 1.f / se;
      float sd[D_CAP], s2 = 0.f;
#pragma unroll
      for (int d = 0; d < D_CAP; ++d) {
        float x = 0.f;
#pragma unroll
        for (int n = 0; n < N_CAP; ++n) x += c[n] * hat[r * HAT_STRIDE + n * D_CAP + d];
        x *= inv;
        sd[d] = x;
        s2 += x * x;
      }
      const float scale = s2 / ((1.f + s2) * sqrtf(s2 + 1e-7f));
#pragma unroll
      for (int d = 0; d < D_CAP; ++d) v[d] = scale * sd[d];
      if (it < 2) {
#pragma unroll
        for (int n = 0; n < N_CAP; ++n) {
          float dd = 0.f;
#pragma unroll
          for (int d = 0; d < D_CAP; ++d) dd += hat[r * HAT_STRIDE + n * D_CAP + d] * v[d];
          bb[n] += dd;
        }
      }
    }
#pragma unroll
    for (int d = 0; d < D_CAP; ++d)
      out[(size_t)(rbase + r) * D_CAP + d] = v[d];
  }
}

extern "C" void kernel_launch(void* const* d_in, const int* in_sizes, int n_in,
                              void* d_out, int out_size, void* d_ws, size_t ws_size,
                              hipStream_t stream) {
  const float* X = (const float*)d_in[0];   // inputs [16384][2048] f32
  const float* W = (const float*)d_in[1];   // kernel [2048][160] f32
  if (n_in >= 2 && in_sizes[0] == KK * NN) {  // defensive: identify by element count
    X = (const float*)d_in[1];
    W = (const float*)d_in[0];
  }
  capsule_fused<<<16384 / BM, THREADS, 0, stream>>>(X, W, (float*)d_out);
}